// Round 3
// baseline (2036.920 us; speedup 1.0000x reference)
//
#include <hip/hip_runtime.h>
#include <math.h>

static constexpr int NU    = 100000;
static constexpr int NI    = 50000;
static constexpr int NEDGE = 1600000;
static constexpr int DIM   = 128;

// ---------------- degree count ----------------
__global__ void count_deg_kernel(const int* __restrict__ src, const int* __restrict__ dst,
                                 int* __restrict__ deg_s, int* __restrict__ deg_d, int n) {
  int stride = gridDim.x * blockDim.x;
  for (int i = blockIdx.x * blockDim.x + threadIdx.x; i < n; i += stride) {
    atomicAdd(&deg_s[src[i]], 1);
    atomicAdd(&deg_d[dst[i]], 1);
  }
}

// in-place int degree -> float 1/sqrt(deg) (bits stored through int* to avoid TBAA issues)
__global__ void inv_sqrt_kernel(int* __restrict__ p, int n) {
  int i = blockIdx.x * blockDim.x + threadIdx.x;
  if (i < n) {
    int v = p[i];
    float f = (v > 0) ? (1.0f / sqrtf((float)v)) : 0.0f;
    p[i] = __float_as_int(f);
  }
}

// ---------------- single-block exclusive scan (ITEMS=4 per thread) ----------------
__global__ __launch_bounds__(1024) void scan_kernel(const int* __restrict__ deg, int n,
                                                    int* __restrict__ rp) {
  __shared__ int wsum[16];
  __shared__ int carry_s;
  const int tid = threadIdx.x, lane = tid & 63, wid = tid >> 6;
  if (tid == 0) carry_s = 0;
  __syncthreads();
  for (int base = 0; base < n; base += 4096) {
    int i0 = base + tid * 4;
    int v0 = 0, v1 = 0, v2 = 0, v3 = 0;
    if (i0 + 3 < n) {
      int4 t = *(const int4*)(deg + i0);
      v0 = t.x; v1 = t.y; v2 = t.z; v3 = t.w;
    } else {
      if (i0     < n) v0 = deg[i0];
      if (i0 + 1 < n) v1 = deg[i0 + 1];
      if (i0 + 2 < n) v2 = deg[i0 + 2];
    }
    int s0 = v0, s1 = s0 + v1, s2 = s1 + v2, s3 = s2 + v3;  // inclusive within thread
    int tot = s3;
    int x = tot;
#pragma unroll
    for (int d2 = 1; d2 < 64; d2 <<= 1) { int y = __shfl_up(x, d2); if (lane >= d2) x += y; }
    if (lane == 63) wsum[wid] = x;
    __syncthreads();
    if (wid == 0) {
      int s = (lane < 16) ? wsum[lane] : 0;
#pragma unroll
      for (int d2 = 1; d2 < 16; d2 <<= 1) { int y = __shfl_up(s, d2); if (lane >= d2) s += y; }
      if (lane < 16) wsum[lane] = s;
    }
    __syncthreads();
    int carry = carry_s;
    int woff = (wid > 0) ? wsum[wid - 1] : 0;
    int base_excl = carry + woff + (x - tot);
    if (i0     < n) rp[i0]     = base_excl;
    if (i0 + 1 < n) rp[i0 + 1] = base_excl + s0;
    if (i0 + 2 < n) rp[i0 + 2] = base_excl + s1;
    if (i0 + 3 < n) rp[i0 + 3] = base_excl + s2;
    __syncthreads();
    if (tid == 0) carry_s = carry + wsum[15];
    __syncthreads();
  }
  if (tid == 0) rp[n] = carry_s;
}

// ---------------- CSR fill ----------------
__global__ void fill_kernel(const int* __restrict__ src, const int* __restrict__ dst,
                            const int* __restrict__ rp, int* __restrict__ cnt,
                            int* __restrict__ csr, int n) {
  int stride = gridDim.x * blockDim.x;
  for (int i = blockIdx.x * blockDim.x + threadIdx.x; i < n; i += stride) {
    int d = dst[i];
    int p = atomicAdd(&cnt[d], 1);
    csr[rp[d] + p] = src[i];
  }
}

// ---------------- fp32 GEMM: C[M,128] = A[M,128] @ W[128,128] ----------------
__global__ __launch_bounds__(256) void gemm128_kernel(const float* __restrict__ A,
                                                      const float* __restrict__ W,
                                                      float* __restrict__ C, int M) {
  __shared__ float As[16][132];   // [k][m], padded to dodge bank conflicts on writes
  __shared__ float Bs[16][128];   // [k][n]
  const int tid = threadIdx.x;
  const int tx = tid & 15, ty = tid >> 4;
  const int row0 = blockIdx.x * 128;
  float acc[8][8];
#pragma unroll
  for (int r = 0; r < 8; ++r)
#pragma unroll
    for (int c = 0; c < 8; ++c) acc[r][c] = 0.f;

  for (int kk = 0; kk < DIM; kk += 16) {
#pragma unroll
    for (int p = 0; p < 2; ++p) {
      int r = (tid >> 2) + p * 64;
      int kc = (tid & 3) * 4;
      float4 a = make_float4(0.f, 0.f, 0.f, 0.f);
      int row = row0 + r;
      if (row < M) a = *(const float4*)(A + (size_t)row * DIM + kk + kc);
      As[kc + 0][r] = a.x; As[kc + 1][r] = a.y; As[kc + 2][r] = a.z; As[kc + 3][r] = a.w;
    }
    {
      const float4* srcp = (const float4*)(W + kk * DIM);
      float4* dstp = (float4*)(&Bs[0][0]);
      dstp[tid]       = srcp[tid];
      dstp[tid + 256] = srcp[tid + 256];
    }
    __syncthreads();
#pragma unroll
    for (int k = 0; k < 16; ++k) {
      float a[8], b[8];
      *(float4*)&a[0] = *(const float4*)&As[k][ty * 8];
      *(float4*)&a[4] = *(const float4*)&As[k][ty * 8 + 4];
      *(float4*)&b[0] = *(const float4*)&Bs[k][tx * 8];
      *(float4*)&b[4] = *(const float4*)&Bs[k][tx * 8 + 4];
#pragma unroll
      for (int r = 0; r < 8; ++r)
#pragma unroll
        for (int c = 0; c < 8; ++c) acc[r][c] += a[r] * b[c];
    }
    __syncthreads();
  }
#pragma unroll
  for (int r = 0; r < 8; ++r) {
    int row = row0 + ty * 8 + r;
    if (row < M) {
      float4* cp = (float4*)(C + (size_t)row * DIM + tx * 8);
      cp[0] = make_float4(acc[r][0], acc[r][1], acc[r][2], acc[r][3]);
      cp[1] = make_float4(acc[r][4], acc[r][5], acc[r][6], acc[r][7]);
    }
  }
}

// ---------------- aggregation: one wave per dst row ----------------
// MODE 0: out = agg
// MODE 1: out = maybe_relu(scale * (out_prev + agg + b1 + b2))
// MODE 2: out = maybe_relu(scale * (agg + b1 [+ b2]))
template <int MODE, bool RELU>
__global__ __launch_bounds__(256) void agg_kernel(const float* __restrict__ h,
                                                  const int* __restrict__ rp,
                                                  const int* __restrict__ csr,
                                                  const float* __restrict__ inv_s,
                                                  const float* __restrict__ inv_d,
                                                  float* __restrict__ out, int n_dst,
                                                  float scale,
                                                  const float* __restrict__ b1,
                                                  const float* __restrict__ b2) {
  const int lane = threadIdx.x & 63;
  const int row = blockIdx.x * (blockDim.x >> 6) + (threadIdx.x >> 6);
  if (row >= n_dst) return;
  const int e0 = rp[row], e1 = rp[row + 1];
  float ax = 0.f, ay = 0.f;
  for (int base = e0; base < e1; base += 64) {
    const int rem = e1 - base;
    const int m = rem < 64 ? rem : 64;
    int s_l = 0; float w_l = 0.f;
    if (lane < m) { s_l = csr[base + lane]; w_l = inv_s[s_l]; }
    int j = 0;
    for (; j + 3 < m; j += 4) {
      int s0 = __shfl(s_l, j), s1 = __shfl(s_l, j + 1), s2 = __shfl(s_l, j + 2), s3 = __shfl(s_l, j + 3);
      float w0 = __shfl(w_l, j), w1 = __shfl(w_l, j + 1), w2 = __shfl(w_l, j + 2), w3 = __shfl(w_l, j + 3);
      float2 v0 = ((const float2*)(h + (size_t)s0 * DIM))[lane];
      float2 v1 = ((const float2*)(h + (size_t)s1 * DIM))[lane];
      float2 v2 = ((const float2*)(h + (size_t)s2 * DIM))[lane];
      float2 v3 = ((const float2*)(h + (size_t)s3 * DIM))[lane];
      ax += w0 * v0.x + w1 * v1.x + w2 * v2.x + w3 * v3.x;
      ay += w0 * v0.y + w1 * v1.y + w2 * v2.y + w3 * v3.y;
    }
    for (; j < m; ++j) {
      int s0 = __shfl(s_l, j); float w0 = __shfl(w_l, j);
      float2 v0 = ((const float2*)(h + (size_t)s0 * DIM))[lane];
      ax += w0 * v0.x; ay += w0 * v0.y;
    }
  }
  const float invd = inv_d[row];
  float rx = ax * invd, ry = ay * invd;
  float2* op = (float2*)(out + (size_t)row * DIM);
  if (MODE == 0) {
    op[lane] = make_float2(rx, ry);
  } else {
    float bx = 0.f, by = 0.f;
    if (b1) { float2 b = ((const float2*)b1)[lane]; bx += b.x; by += b.y; }
    if (b2) { float2 b = ((const float2*)b2)[lane]; bx += b.x; by += b.y; }
    float px = 0.f, py = 0.f;
    if (MODE == 1) { float2 p = op[lane]; px = p.x; py = p.y; }
    float vx = scale * (px + rx + bx), vy = scale * (py + ry + by);
    if (RELU) { vx = fmaxf(vx, 0.f); vy = fmaxf(vy, 0.f); }
    op[lane] = make_float2(vx, vy);
  }
}

extern "C" void kernel_launch(void* const* d_in, const int* in_sizes, int n_in,
                              void* d_out, int out_size, void* d_ws, size_t ws_size,
                              hipStream_t stream) {
  const float* x_user = (const float*)d_in[0];
  const float* x_item = (const float*)d_in[1];
  const int* f_src = (const int*)d_in[2];
  const int* f_dst = (const int*)d_in[3];
  const int* r_src = (const int*)d_in[4];
  const int* r_dst = (const int*)d_in[5];
  const int* v_src = (const int*)d_in[6];
  const int* v_dst = (const int*)d_in[7];
  const float* W1f = (const float*)d_in[8];
  const float* W1r = (const float*)d_in[9];
  const float* W1v = (const float*)d_in[10];
  const float* W2f = (const float*)d_in[11];
  const float* W2r = (const float*)d_in[12];
  const float* W2v = (const float*)d_in[13];
  const float* b1f = (const float*)d_in[14];
  const float* b1r = (const float*)d_in[15];
  const float* b1v = (const float*)d_in[16];
  const float* b2f = (const float*)d_in[17];
  const float* b2r = (const float*)d_in[18];
  const float* b2v = (const float*)d_in[19];

  char* ws = (char*)d_ws;
  size_t off = 0;
  auto alloc = [&](size_t bytes) {
    size_t o = off;
    off = (off + bytes + 511) & ~(size_t)511;
    return o;
  };
  size_t o_deg = alloc(4ull * (4 * NU + 2 * NI));
  size_t o_rpf = alloc(4ull * (NU + 1));
  size_t o_rpr = alloc(4ull * (NI + 1));
  size_t o_rpv = alloc(4ull * (NU + 1));
  size_t o_cnt = alloc(4ull * (2 * NU + NI));
  size_t o_csf = alloc(4ull * NEDGE);
  size_t o_csr = alloc(4ull * NEDGE);
  size_t o_csv = alloc(4ull * NEDGE);
  size_t o_h   = alloc(4ull * NU * DIM);
  size_t o_u   = alloc(4ull * NU * DIM);
  size_t o_it  = alloc(4ull * NI * DIM);
  (void)ws_size; (void)in_sizes; (void)n_in; (void)out_size;

  int* deg    = (int*)(ws + o_deg);
  int* deg_fs = deg;                 // N_U
  int* deg_fd = deg + NU;            // N_U
  int* deg_rs = deg + 2 * NU;        // N_U
  int* deg_rd = deg + 3 * NU;        // N_I
  int* deg_vs = deg + 3 * NU + NI;   // N_I
  int* deg_vd = deg + 3 * NU + 2 * NI; // N_U

  int* rp_f = (int*)(ws + o_rpf);
  int* rp_r = (int*)(ws + o_rpr);
  int* rp_v = (int*)(ws + o_rpv);
  int* cnt   = (int*)(ws + o_cnt);
  int* cnt_f = cnt;
  int* cnt_r = cnt + NU;
  int* cnt_v = cnt + NU + NI;
  int* csr_f = (int*)(ws + o_csf);
  int* csr_r = (int*)(ws + o_csr);
  int* csr_v = (int*)(ws + o_csv);
  float* h  = (float*)(ws + o_h);
  float* u  = (float*)(ws + o_u);
  float* it = (float*)(ws + o_it);

  float* out_u = (float*)d_out;
  float* out_i = out_u + (size_t)NU * DIM;

  hipMemsetAsync(deg, 0, 4ull * (4 * NU + 2 * NI), stream);
  hipMemsetAsync(cnt, 0, 4ull * (2 * NU + NI), stream);

  count_deg_kernel<<<2048, 256, 0, stream>>>(f_src, f_dst, deg_fs, deg_fd, NEDGE);
  count_deg_kernel<<<2048, 256, 0, stream>>>(r_src, r_dst, deg_rs, deg_rd, NEDGE);
  count_deg_kernel<<<2048, 256, 0, stream>>>(v_src, v_dst, deg_vs, deg_vd, NEDGE);

  scan_kernel<<<1, 1024, 0, stream>>>(deg_fd, NU, rp_f);
  scan_kernel<<<1, 1024, 0, stream>>>(deg_rd, NI, rp_r);
  scan_kernel<<<1, 1024, 0, stream>>>(deg_vd, NU, rp_v);

  inv_sqrt_kernel<<<(4 * NU + 2 * NI + 255) / 256, 256, 0, stream>>>(deg, 4 * NU + 2 * NI);

  fill_kernel<<<2048, 256, 0, stream>>>(f_src, f_dst, rp_f, cnt_f, csr_f, NEDGE);
  fill_kernel<<<2048, 256, 0, stream>>>(r_src, r_dst, rp_r, cnt_r, csr_r, NEDGE);
  fill_kernel<<<2048, 256, 0, stream>>>(v_src, v_dst, rp_v, cnt_v, csr_v, NEDGE);

  const float* inv_fs = (const float*)deg_fs;
  const float* inv_fd = (const float*)deg_fd;
  const float* inv_rs = (const float*)deg_rs;
  const float* inv_rd = (const float*)deg_rd;
  const float* inv_vs = (const float*)deg_vs;
  const float* inv_vd = (const float*)deg_vd;

  // ---------------- layer 1 ----------------
  gemm128_kernel<<<(NU + 127) / 128, 256, 0, stream>>>(x_user, W1f, h, NU);
  agg_kernel<0, false><<<(NU + 3) / 4, 256, 0, stream>>>(h, rp_f, csr_f, inv_fs, inv_fd,
                                                         u, NU, 1.0f, nullptr, nullptr);
  gemm128_kernel<<<(NI + 127) / 128, 256, 0, stream>>>(x_item, W1v, h, NI);
  agg_kernel<1, true><<<(NU + 3) / 4, 256, 0, stream>>>(h, rp_v, csr_v, inv_vs, inv_vd,
                                                        u, NU, 0.5f, b1f, b1v);
  gemm128_kernel<<<(NU + 127) / 128, 256, 0, stream>>>(x_user, W1r, h, NU);
  agg_kernel<2, true><<<(NI + 3) / 4, 256, 0, stream>>>(h, rp_r, csr_r, inv_rs, inv_rd,
                                                        it, NI, 1.0f, b1r, nullptr);

  // ---------------- layer 2 ----------------
  gemm128_kernel<<<(NU + 127) / 128, 256, 0, stream>>>(u, W2f, h, NU);
  agg_kernel<0, false><<<(NU + 3) / 4, 256, 0, stream>>>(h, rp_f, csr_f, inv_fs, inv_fd,
                                                         out_u, NU, 1.0f, nullptr, nullptr);
  gemm128_kernel<<<(NI + 127) / 128, 256, 0, stream>>>(it, W2v, h, NI);
  agg_kernel<1, false><<<(NU + 3) / 4, 256, 0, stream>>>(h, rp_v, csr_v, inv_vs, inv_vd,
                                                         out_u, NU, 0.5f, b2f, b2v);
  gemm128_kernel<<<(NU + 127) / 128, 256, 0, stream>>>(u, W2r, h, NU);
  agg_kernel<2, false><<<(NI + 3) / 4, 256, 0, stream>>>(h, rp_r, csr_r, inv_rs, inv_rd,
                                                         out_i, NI, 1.0f, b2r, nullptr);
}

// Round 5
// 1945.422 us; speedup vs baseline: 1.0470x; 1.0470x over previous
//
#include <hip/hip_runtime.h>
#include <math.h>

static constexpr int NU    = 100000;
static constexpr int NI    = 50000;
static constexpr int NEDGE = 1600000;
static constexpr int DIM   = 128;

// grid-role constants
static constexpr int CB  = 768;                 // count blocks in k1
static constexpr int GF  = (NU + 127) / 128;    // 782 gemm blocks (NU)
static constexpr int GV  = (NI + 127) / 128;    // 391 gemm blocks (NI)
static constexpr int FB  = 512;                 // fill blocks per relation
static constexpr int AGU = (NU + 3) / 4;        // 25000 agg blocks (user dst)
static constexpr int AGI = (NI + 3) / 4;        // 12500 agg blocks (item dst)

// ---------------- count + rank (atomic returns old value = rank within dst) ----------------
__device__ __forceinline__ void count_rel(const int* __restrict__ src, const int* __restrict__ dst,
                                          int* __restrict__ deg_s, int* __restrict__ deg_d,
                                          int* __restrict__ rank, int blk, int nblk) {
  const int nchunk = NEDGE / 4;
  const int stride = nblk * 256;
  for (int c = blk * 256 + threadIdx.x; c < nchunk; c += stride) {
    int4 s = ((const int4*)src)[c];
    int4 d = ((const int4*)dst)[c];
    atomicAdd(&deg_s[s.x], 1);
    atomicAdd(&deg_s[s.y], 1);
    atomicAdd(&deg_s[s.z], 1);
    atomicAdd(&deg_s[s.w], 1);
    int4 r;
    r.x = atomicAdd(&deg_d[d.x], 1);
    r.y = atomicAdd(&deg_d[d.y], 1);
    r.z = atomicAdd(&deg_d[d.z], 1);
    r.w = atomicAdd(&deg_d[d.w], 1);
    ((int4*)rank)[c] = r;
  }
}

// ---------------- atomic-free CSR fill (pure scatter) ----------------
__device__ __forceinline__ void fill_rel(const int* __restrict__ src, const int* __restrict__ dst,
                                         const int* __restrict__ rank, const int* __restrict__ rp,
                                         int* __restrict__ csr, int blk, int nblk) {
  const int nchunk = NEDGE / 4;
  const int stride = nblk * 256;
  for (int c = blk * 256 + threadIdx.x; c < nchunk; c += stride) {
    int4 s = ((const int4*)src)[c];
    int4 d = ((const int4*)dst)[c];
    int4 r = ((const int4*)rank)[c];
    csr[rp[d.x] + r.x] = s.x;
    csr[rp[d.y] + r.y] = s.y;
    csr[rp[d.z] + r.z] = s.z;
    csr[rp[d.w] + r.w] = s.w;
  }
}

// ---------------- fp32 GEMM body: C[M,128] = A[M,128] @ W[128,128] ----------------
__device__ __forceinline__ void gemm_body(const float* __restrict__ A, const float* __restrict__ W,
                                          float* __restrict__ C, int M, int blk) {
  static __shared__ float As[16][132];
  static __shared__ float Bs[16][128];
  const int tid = threadIdx.x;
  const int tx = tid & 15, ty = tid >> 4;
  const int row0 = blk * 128;
  float acc[8][8];
#pragma unroll
  for (int r = 0; r < 8; ++r)
#pragma unroll
    for (int c = 0; c < 8; ++c) acc[r][c] = 0.f;

  for (int kk = 0; kk < DIM; kk += 16) {
#pragma unroll
    for (int p = 0; p < 2; ++p) {
      int r = (tid >> 2) + p * 64;
      int kc = (tid & 3) * 4;
      float4 a = make_float4(0.f, 0.f, 0.f, 0.f);
      int row = row0 + r;
      if (row < M) a = *(const float4*)(A + (size_t)row * DIM + kk + kc);
      As[kc + 0][r] = a.x; As[kc + 1][r] = a.y; As[kc + 2][r] = a.z; As[kc + 3][r] = a.w;
    }
    {
      const float4* srcp = (const float4*)(W + kk * DIM);
      float4* dstp = (float4*)(&Bs[0][0]);
      dstp[tid]       = srcp[tid];
      dstp[tid + 256] = srcp[tid + 256];
    }
    __syncthreads();
#pragma unroll
    for (int k = 0; k < 16; ++k) {
      float a[8], b[8];
      *(float4*)&a[0] = *(const float4*)&As[k][ty * 8];
      *(float4*)&a[4] = *(const float4*)&As[k][ty * 8 + 4];
      *(float4*)&b[0] = *(const float4*)&Bs[k][tx * 8];
      *(float4*)&b[4] = *(const float4*)&Bs[k][tx * 8 + 4];
#pragma unroll
      for (int r = 0; r < 8; ++r)
#pragma unroll
        for (int c = 0; c < 8; ++c) acc[r][c] += a[r] * b[c];
    }
    __syncthreads();
  }
#pragma unroll
  for (int r = 0; r < 8; ++r) {
    int row = row0 + ty * 8 + r;
    if (row < M) {
      float4* cp = (float4*)(C + (size_t)row * DIM + tx * 8);
      cp[0] = make_float4(acc[r][0], acc[r][1], acc[r][2], acc[r][3]);
      cp[1] = make_float4(acc[r][4], acc[r][5], acc[r][6], acc[r][7]);
    }
  }
}

// ---------------- aggregation rows (one wave per dst row) ----------------
// MODE 0: out = agg ; MODE 1: out = maybe_relu(scale*(out_prev+agg+b1+b2)) ; MODE 2: out = maybe_relu(scale*(agg+b1))
template <int MODE, bool RELU>
__device__ __forceinline__ void agg_rows(const float* __restrict__ h, const int* __restrict__ rp,
                                         const int* __restrict__ csr, const float* __restrict__ inv_s,
                                         const float* __restrict__ inv_d, float* __restrict__ out,
                                         int n_dst, float scale, const float* __restrict__ b1,
                                         const float* __restrict__ b2, int blk) {
  const int lane = threadIdx.x & 63;
  const int row = blk * 4 + (threadIdx.x >> 6);
  if (row >= n_dst) return;
  const int e0 = rp[row], e1 = rp[row + 1];
  float ax = 0.f, ay = 0.f;
  for (int base = e0; base < e1; base += 64) {
    const int rem = e1 - base;
    const int m = rem < 64 ? rem : 64;
    int s_l = 0; float w_l = 0.f;
    if (lane < m) { s_l = csr[base + lane]; w_l = inv_s[s_l]; }
    int j = 0;
    for (; j + 3 < m; j += 4) {
      int s0 = __shfl(s_l, j), s1 = __shfl(s_l, j + 1), s2 = __shfl(s_l, j + 2), s3 = __shfl(s_l, j + 3);
      float w0 = __shfl(w_l, j), w1 = __shfl(w_l, j + 1), w2 = __shfl(w_l, j + 2), w3 = __shfl(w_l, j + 3);
      float2 v0 = ((const float2*)(h + (size_t)s0 * DIM))[lane];
      float2 v1 = ((const float2*)(h + (size_t)s1 * DIM))[lane];
      float2 v2 = ((const float2*)(h + (size_t)s2 * DIM))[lane];
      float2 v3 = ((const float2*)(h + (size_t)s3 * DIM))[lane];
      ax += w0 * v0.x + w1 * v1.x + w2 * v2.x + w3 * v3.x;
      ay += w0 * v0.y + w1 * v1.y + w2 * v2.y + w3 * v3.y;
    }
    for (; j < m; ++j) {
      int s0 = __shfl(s_l, j); float w0 = __shfl(w_l, j);
      float2 v0 = ((const float2*)(h + (size_t)s0 * DIM))[lane];
      ax += w0 * v0.x; ay += w0 * v0.y;
    }
  }
  const float invd = inv_d[row];
  float rx = ax * invd, ry = ay * invd;
  float2* op = (float2*)(out + (size_t)row * DIM);
  if (MODE == 0) {
    op[lane] = make_float2(rx, ry);
  } else {
    float bx = 0.f, by = 0.f;
    if (b1) { float2 b = ((const float2*)b1)[lane]; bx += b.x; by += b.y; }
    if (b2) { float2 b = ((const float2*)b2)[lane]; bx += b.x; by += b.y; }
    float px = 0.f, py = 0.f;
    if (MODE == 1) { float2 p = op[lane]; px = p.x; py = p.y; }
    float vx = scale * (px + rx + bx), vy = scale * (py + ry + by);
    if (RELU) { vx = fmaxf(vx, 0.f); vy = fmaxf(vy, 0.f); }
    op[lane] = make_float2(vx, vy);
  }
}

// ---------------- single-block scan body ----------------
__device__ void scan_body(const int* __restrict__ deg, int n, int* __restrict__ rp) {
  static __shared__ int wsum[16];
  static __shared__ int carry_s;
  const int tid = threadIdx.x, lane = tid & 63, wid = tid >> 6;
  if (tid == 0) carry_s = 0;
  __syncthreads();
  for (int base = 0; base < n; base += 4096) {
    int i0 = base + tid * 4;
    int v0 = 0, v1 = 0, v2 = 0, v3 = 0;
    if (i0 + 3 < n) {
      int4 t = *(const int4*)(deg + i0);
      v0 = t.x; v1 = t.y; v2 = t.z; v3 = t.w;
    } else {
      if (i0     < n) v0 = deg[i0];
      if (i0 + 1 < n) v1 = deg[i0 + 1];
      if (i0 + 2 < n) v2 = deg[i0 + 2];
    }
    int s0 = v0, s1 = s0 + v1, s2 = s1 + v2, s3 = s2 + v3;
    int tot = s3;
    int x = tot;
#pragma unroll
    for (int d2 = 1; d2 < 64; d2 <<= 1) { int y = __shfl_up(x, d2); if (lane >= d2) x += y; }
    if (lane == 63) wsum[wid] = x;
    __syncthreads();
    if (wid == 0) {
      int s = (lane < 16) ? wsum[lane] : 0;
#pragma unroll
      for (int d2 = 1; d2 < 16; d2 <<= 1) { int y = __shfl_up(s, d2); if (lane >= d2) s += y; }
      if (lane < 16) wsum[lane] = s;
    }
    __syncthreads();
    int carry = carry_s;
    int woff = (wid > 0) ? wsum[wid - 1] : 0;
    int base_excl = carry + woff + (x - tot);
    if (i0     < n) rp[i0]     = base_excl;
    if (i0 + 1 < n) rp[i0 + 1] = base_excl + s0;
    if (i0 + 2 < n) rp[i0 + 2] = base_excl + s1;
    if (i0 + 3 < n) rp[i0 + 3] = base_excl + s2;
    __syncthreads();
    if (tid == 0) carry_s = carry + wsum[15];
    __syncthreads();
  }
  if (tid == 0) rp[n] = carry_s;
}

// =================== kernels ===================

// K1: count all 3 relations (blocks [0,CB)) ∥ layer-1 GEMMs
__global__ __launch_bounds__(256) void k1_kernel(
    const int* f_src, const int* f_dst, int* deg_fs, int* deg_fd, int* rank_f,
    const int* r_src, const int* r_dst, int* deg_rs, int* deg_rd, int* rank_r,
    const int* v_src, const int* v_dst, int* deg_vs, int* deg_vd, int* rank_v,
    const float* x_user, const float* x_item,
    const float* W1f, const float* W1v, const float* W1r,
    float* h_f, float* h_v, float* h_r) {
  int b = blockIdx.x;
  if (b < CB) {
    count_rel(f_src, f_dst, deg_fs, deg_fd, rank_f, b, CB);
    count_rel(r_src, r_dst, deg_rs, deg_rd, rank_r, b, CB);
    count_rel(v_src, v_dst, deg_vs, deg_vd, rank_v, b, CB);
  } else if (b < CB + GF) {
    gemm_body(x_user, W1f, h_f, NU, b - CB);
  } else if (b < CB + GF + GV) {
    gemm_body(x_item, W1v, h_v, NI, b - CB - GF);
  } else {
    gemm_body(x_user, W1r, h_r, NU, b - CB - GF - GV);
  }
}

__global__ __launch_bounds__(1024) void scan3_kernel(const int* deg_fd, int* rp_f,
                                                     const int* deg_rd, int* rp_r,
                                                     const int* deg_vd, int* rp_v) {
  if (blockIdx.x == 0)      scan_body(deg_fd, NU, rp_f);
  else if (blockIdx.x == 1) scan_body(deg_rd, NI, rp_r);
  else                      scan_body(deg_vd, NU, rp_v);
}

// in-place int degree -> float 1/sqrt(deg)
__global__ void inv_sqrt_kernel(int* __restrict__ p, int n) {
  int i = blockIdx.x * blockDim.x + threadIdx.x;
  if (i < n) {
    int v = p[i];
    float f = (v > 0) ? (1.0f / sqrtf((float)v)) : 0.0f;
    p[i] = __float_as_int(f);
  }
}

__global__ __launch_bounds__(256) void fill_one_kernel(const int* src, const int* dst,
                                                       const int* rank, const int* rp, int* csr) {
  fill_rel(src, dst, rank, rp, csr, blockIdx.x, gridDim.x);
}

__global__ __launch_bounds__(256) void fill_vr_kernel(
    const int* v_src, const int* v_dst, const int* rank_v, const int* rp_v, int* csr_v,
    const int* r_src, const int* r_dst, const int* rank_r, const int* rp_r, int* csr_r) {
  int b = blockIdx.x;
  if (b < FB) fill_rel(v_src, v_dst, rank_v, rp_v, csr_v, b, FB);
  else        fill_rel(r_src, r_dst, rank_r, rp_r, csr_r, b - FB, FB);
}

// K4: fill_v ∥ fill_r ∥ agg_f (h_f -> u, MODE0)
__global__ __launch_bounds__(256) void k4_kernel(
    const int* v_src, const int* v_dst, const int* rank_v, const int* rp_v, int* csr_v,
    const int* r_src, const int* r_dst, const int* rank_r, const int* rp_r, int* csr_r,
    const float* h_f, const int* rp_f, const int* csr_f,
    const float* inv_fs, const float* inv_fd, float* u) {
  int b = blockIdx.x;
  if (b < FB)          fill_rel(v_src, v_dst, rank_v, rp_v, csr_v, b, FB);
  else if (b < 2 * FB) fill_rel(r_src, r_dst, rank_r, rp_r, csr_r, b - FB, FB);
  else agg_rows<0, false>(h_f, rp_f, csr_f, inv_fs, inv_fd, u, NU, 1.0f, nullptr, nullptr, b - 2 * FB);
}

// K5: agg_v (MODE1 relu -> u) ∥ agg_r (MODE2 relu -> it)
__global__ __launch_bounds__(256) void k5_kernel(
    const float* h_v, const int* rp_v, const int* csr_v, const float* inv_vs, const float* inv_vd,
    float* u, const float* b1f, const float* b1v,
    const float* h_r, const int* rp_r, const int* csr_r, const float* inv_rs, const float* inv_rd,
    float* it, const float* b1r) {
  int b = blockIdx.x;
  if (b < AGU) agg_rows<1, true>(h_v, rp_v, csr_v, inv_vs, inv_vd, u, NU, 0.5f, b1f, b1v, b);
  else         agg_rows<2, true>(h_r, rp_r, csr_r, inv_rs, inv_rd, it, NI, 1.0f, b1r, nullptr, b - AGU);
}

__global__ __launch_bounds__(256) void gemm_one_kernel(const float* A, const float* W, float* C, int M) {
  gemm_body(A, W, C, M, blockIdx.x);
}

// K7: g2v (it@W2v->h_v) ∥ g2r (u@W2r->h_r) ∥ agg2_f (h_f -> out_u, MODE0)
__global__ __launch_bounds__(256) void k7_kernel(
    const float* it, const float* W2v, float* h_v,
    const float* u,  const float* W2r, float* h_r,
    const float* h_f, const int* rp_f, const int* csr_f,
    const float* inv_fs, const float* inv_fd, float* out_u) {
  int b = blockIdx.x;
  if (b < GV)           gemm_body(it, W2v, h_v, NI, b);
  else if (b < GV + GF) gemm_body(u, W2r, h_r, NU, b - GV);
  else agg_rows<0, false>(h_f, rp_f, csr_f, inv_fs, inv_fd, out_u, NU, 1.0f, nullptr, nullptr, b - GV - GF);
}

// K8: agg2_v (MODE1 -> out_u) ∥ agg2_r (MODE2 -> out_i), no relu
__global__ __launch_bounds__(256) void k8_kernel(
    const float* h_v, const int* rp_v, const int* csr_v, const float* inv_vs, const float* inv_vd,
    float* out_u, const float* b2f, const float* b2v,
    const float* h_r, const int* rp_r, const int* csr_r, const float* inv_rs, const float* inv_rd,
    float* out_i, const float* b2r) {
  int b = blockIdx.x;
  if (b < AGU) agg_rows<1, false>(h_v, rp_v, csr_v, inv_vs, inv_vd, out_u, NU, 0.5f, b2f, b2v, b);
  else         agg_rows<2, false>(h_r, rp_r, csr_r, inv_rs, inv_rd, out_i, NI, 1.0f, b2r, nullptr, b - AGU);
}

// standalone agg for fallback path
template <int MODE, bool RELU>
__global__ __launch_bounds__(256) void agg_kernel(const float* h, const int* rp, const int* csr,
                                                  const float* inv_s, const float* inv_d,
                                                  float* out, int n_dst, float scale,
                                                  const float* b1, const float* b2) {
  agg_rows<MODE, RELU>(h, rp, csr, inv_s, inv_d, out, n_dst, scale, b1, b2, blockIdx.x);
}

extern "C" void kernel_launch(void* const* d_in, const int* in_sizes, int n_in,
                              void* d_out, int out_size, void* d_ws, size_t ws_size,
                              hipStream_t stream) {
  const float* x_user = (const float*)d_in[0];
  const float* x_item = (const float*)d_in[1];
  const int* f_src = (const int*)d_in[2];
  const int* f_dst = (const int*)d_in[3];
  const int* r_src = (const int*)d_in[4];
  const int* r_dst = (const int*)d_in[5];
  const int* v_src = (const int*)d_in[6];
  const int* v_dst = (const int*)d_in[7];
  const float* W1f = (const float*)d_in[8];
  const float* W1r = (const float*)d_in[9];
  const float* W1v = (const float*)d_in[10];
  const float* W2f = (const float*)d_in[11];
  const float* W2r = (const float*)d_in[12];
  const float* W2v = (const float*)d_in[13];
  const float* b1f = (const float*)d_in[14];
  const float* b1r = (const float*)d_in[15];
  const float* b1v = (const float*)d_in[16];
  const float* b2f = (const float*)d_in[17];
  const float* b2r = (const float*)d_in[18];
  const float* b2v = (const float*)d_in[19];
  (void)in_sizes; (void)n_in; (void)out_size;

  char* ws = (char*)d_ws;
  size_t off = 0;
  auto alloc = [&](size_t bytes) {
    size_t o = off;
    off = (off + bytes + 511) & ~(size_t)511;
    return o;
  };
  // common layout
  size_t o_deg = alloc(4ull * (4 * NU + 2 * NI));   // 6 degree arrays, contiguous
  size_t o_rpf = alloc(4ull * (NU + 1));
  size_t o_rpr = alloc(4ull * (NI + 1));
  size_t o_rpv = alloc(4ull * (NU + 1));
  size_t o_csf = alloc(4ull * NEDGE);
  size_t o_csr = alloc(4ull * NEDGE);
  size_t o_csv = alloc(4ull * NEDGE);
  size_t o_it  = alloc(4ull * NI * DIM);
  size_t o_hf  = alloc(4ull * NU * DIM);
  size_t o_u   = alloc(4ull * NU * DIM);
  size_t small_need = off + 512;      // fallback: ranks alias u
  size_t o_hv  = alloc(4ull * NI * DIM);
  size_t o_hr  = alloc(4ull * NU * DIM);
  size_t o_rkf = alloc(4ull * NEDGE);
  size_t o_rkr = alloc(4ull * NEDGE);
  size_t o_rkv = alloc(4ull * NEDGE);
  size_t big_need = off + 512;

  const bool big = (ws_size >= big_need);

  int* deg    = (int*)(ws + o_deg);
  int* deg_fs = deg;
  int* deg_fd = deg + NU;
  int* deg_rs = deg + 2 * NU;
  int* deg_rd = deg + 3 * NU;
  int* deg_vs = deg + 3 * NU + NI;
  int* deg_vd = deg + 3 * NU + 2 * NI;

  int* rp_f = (int*)(ws + o_rpf);
  int* rp_r = (int*)(ws + o_rpr);
  int* rp_v = (int*)(ws + o_rpv);
  int* csr_f = (int*)(ws + o_csf);
  int* csr_r = (int*)(ws + o_csr);
  int* csr_v = (int*)(ws + o_csv);
  float* it  = (float*)(ws + o_it);
  float* h_f = (float*)(ws + o_hf);
  float* u   = (float*)(ws + o_u);
  // big: dedicated buffers; fallback: h_v/h_r alias h_f, ranks alias u (dead before u is written)
  float* h_v = big ? (float*)(ws + o_hv) : h_f;
  float* h_r = big ? (float*)(ws + o_hr) : h_f;
  int* rank_f = big ? (int*)(ws + o_rkf) : (int*)(ws + o_u);
  int* rank_r = big ? (int*)(ws + o_rkr) : (int*)(ws + o_u) + NEDGE;
  int* rank_v = big ? (int*)(ws + o_rkv) : (int*)(ws + o_u) + 2 * NEDGE;
  (void)small_need;

  float* out_u = (float*)d_out;
  float* out_i = out_u + (size_t)NU * DIM;

  const float* inv_fs = (const float*)deg_fs;
  const float* inv_fd = (const float*)deg_fd;
  const float* inv_rs = (const float*)deg_rs;
  const float* inv_rd = (const float*)deg_rd;
  const float* inv_vs = (const float*)deg_vs;
  const float* inv_vd = (const float*)deg_vd;

  hipMemsetAsync(deg, 0, 4ull * (4 * NU + 2 * NI), stream);

  if (big) {
    // K1: count×3 ∥ layer-1 GEMMs
    k1_kernel<<<CB + GF + GV + GF, 256, 0, stream>>>(
        f_src, f_dst, deg_fs, deg_fd, rank_f,
        r_src, r_dst, deg_rs, deg_rd, rank_r,
        v_src, v_dst, deg_vs, deg_vd, rank_v,
        x_user, x_item, W1f, W1v, W1r, h_f, h_v, h_r);
    scan3_kernel<<<3, 1024, 0, stream>>>(deg_fd, rp_f, deg_rd, rp_r, deg_vd, rp_v);
    inv_sqrt_kernel<<<(4 * NU + 2 * NI + 1023) / 1024, 1024, 0, stream>>>(deg, 4 * NU + 2 * NI);
    fill_one_kernel<<<FB, 256, 0, stream>>>(f_src, f_dst, rank_f, rp_f, csr_f);
    // K4: fill_v ∥ fill_r ∥ agg_f
    k4_kernel<<<2 * FB + AGU, 256, 0, stream>>>(
        v_src, v_dst, rank_v, rp_v, csr_v,
        r_src, r_dst, rank_r, rp_r, csr_r,
        h_f, rp_f, csr_f, inv_fs, inv_fd, u);
    // K5: agg_v ∥ agg_r (finish layer 1)
    k5_kernel<<<AGU + AGI, 256, 0, stream>>>(
        h_v, rp_v, csr_v, inv_vs, inv_vd, u, b1f, b1v,
        h_r, rp_r, csr_r, inv_rs, inv_rd, it, b1r);
    // K6: g2f
    gemm_one_kernel<<<GF, 256, 0, stream>>>(u, W2f, h_f, NU);
    // K7: g2v ∥ g2r ∥ agg2_f
    k7_kernel<<<GV + GF + AGU, 256, 0, stream>>>(
        it, W2v, h_v, u, W2r, h_r,
        h_f, rp_f, csr_f, inv_fs, inv_fd, out_u);
    // K8: agg2_v ∥ agg2_r
    k8_kernel<<<AGU + AGI, 256, 0, stream>>>(
        h_v, rp_v, csr_v, inv_vs, inv_vd, out_u, b2f, b2v,
        h_r, rp_r, csr_r, inv_rs, inv_rd, out_i, b2r);
  } else {
    // fallback: single h buffer, ranks alias u (u written only after all fills)
    k1_kernel<<<CB, 256, 0, stream>>>(   // count roles only
        f_src, f_dst, deg_fs, deg_fd, rank_f,
        r_src, r_dst, deg_rs, deg_rd, rank_r,
        v_src, v_dst, deg_vs, deg_vd, rank_v,
        x_user, x_item, W1f, W1v, W1r, h_f, h_v, h_r);
    scan3_kernel<<<3, 1024, 0, stream>>>(deg_fd, rp_f, deg_rd, rp_r, deg_vd, rp_v);
    inv_sqrt_kernel<<<(4 * NU + 2 * NI + 1023) / 1024, 1024, 0, stream>>>(deg, 4 * NU + 2 * NI);
    fill_one_kernel<<<FB, 256, 0, stream>>>(f_src, f_dst, rank_f, rp_f, csr_f);
    fill_vr_kernel<<<2 * FB, 256, 0, stream>>>(
        v_src, v_dst, rank_v, rp_v, csr_v,
        r_src, r_dst, rank_r, rp_r, csr_r);
    gemm_one_kernel<<<GF, 256, 0, stream>>>(x_user, W1f, h_f, NU);
    agg_kernel<0, false><<<AGU, 256, 0, stream>>>(h_f, rp_f, csr_f, inv_fs, inv_fd, u, NU, 1.0f, nullptr, nullptr);
    gemm_one_kernel<<<GV, 256, 0, stream>>>(x_item, W1v, h_f, NI);
    agg_kernel<1, true><<<AGU, 256, 0, stream>>>(h_f, rp_v, csr_v, inv_vs, inv_vd, u, NU, 0.5f, b1f, b1v);
    gemm_one_kernel<<<GF, 256, 0, stream>>>(x_user, W1r, h_f, NU);
    agg_kernel<2, true><<<AGI, 256, 0, stream>>>(h_f, rp_r, csr_r, inv_rs, inv_rd, it, NI, 1.0f, b1r, nullptr);
    gemm_one_kernel<<<GF, 256, 0, stream>>>(u, W2f, h_f, NU);
    agg_kernel<0, false><<<AGU, 256, 0, stream>>>(h_f, rp_f, csr_f, inv_fs, inv_fd, out_u, NU, 1.0f, nullptr, nullptr);
    gemm_one_kernel<<<GV, 256, 0, stream>>>(it, W2v, h_f, NI);
    agg_kernel<1, false><<<AGU, 256, 0, stream>>>(h_f, rp_v, csr_v, inv_vs, inv_vd, out_u, NU, 0.5f, b2f, b2v);
    gemm_one_kernel<<<GF, 256, 0, stream>>>(u, W2r, h_f, NU);
    agg_kernel<2, false><<<AGI, 256, 0, stream>>>(h_f, rp_r, csr_r, inv_rs, inv_rd, out_i, NI, 1.0f, b2r, nullptr);
  }
}